// Round 1
// 437.141 us; speedup vs baseline: 1.0842x; 1.0842x over previous
//
#include <hip/hip_runtime.h>
#include <math.h>

#define S_ 2048
#define R_ 384

typedef __attribute__((ext_vector_type(8))) short bf16x8;
typedef __attribute__((ext_vector_type(4))) float f32x4;

static __device__ __forceinline__ f32x4 mfma16(bf16x8 a, bf16x8 b, f32x4 c) {
  return __builtin_amdgcn_mfma_f32_16x16x32_bf16(a, b, c, 0, 0, 0);
}

// fp32 -> bf16 round-to-nearest-even
static __device__ __forceinline__ unsigned short f2bf(float f) {
  unsigned u = __float_as_uint(f);
  u += 0x7fffu + ((u >> 16) & 1u);
  return (unsigned short)(u >> 16);
}
static __device__ __forceinline__ float bflo(unsigned u) {
  return __uint_as_float(u << 16);
}
static __device__ __forceinline__ float bfhi(unsigned u) {
  return __uint_as_float(u & 0xffff0000u);
}

// LayerNorm of one 64-float row spread across a 16-lane group (lane holds 4
// consecutive c at c4). Wave-synchronous shfl reduction within the group.
__device__ __forceinline__ float4 ln_quad(const float4 x4, const float* lnw,
                                          const float* lnb, int c4) {
  float s1 = x4.x + x4.y + x4.z + x4.w;
  float s2 = fmaf(x4.x, x4.x, fmaf(x4.y, x4.y, fmaf(x4.z, x4.z, x4.w * x4.w)));
#pragma unroll
  for (int msk = 1; msk <= 8; msk <<= 1) {
    s1 += __shfl_xor(s1, msk);
    s2 += __shfl_xor(s2, msk);
  }
  float mu  = s1 * (1.f / 64.f);
  float var = fmaf(-mu, mu, s2 * (1.f / 64.f));
  float inv = rsqrtf(var + 1e-5f);
  float nb  = -mu * inv;
  float4 xl;
  xl.x = fmaf(fmaf(x4.x, inv, nb), lnw[c4 + 0], lnb[c4 + 0]);
  xl.y = fmaf(fmaf(x4.y, inv, nb), lnw[c4 + 1], lnb[c4 + 1]);
  xl.z = fmaf(fmaf(x4.z, inv, nb), lnw[c4 + 2], lnb[c4 + 2]);
  xl.w = fmaf(fmaf(x4.w, inv, nb), lnw[c4 + 3], lnb[c4 + 3]);
  return xl;
}

// ---- Kernel 1: LN + K/V GEMM + gate GEMM + sigmoid + g-store + q partials ----
// grid (8, R), block 256 (4 waves). Block covers 256 s-rows of column r.
// kv bf16 [r][s][16] (k:0-7, v:8-15). g bf16 [s][r][64] (post-sigmoid).
__global__ __launch_bounds__(256) void k_lnkv(
    const float* __restrict__ m, const float* __restrict__ lnw_g,
    const float* __restrict__ lnb_g, const float* __restrict__ Wk,
    const float* __restrict__ Wv, const float* __restrict__ Wg,
    const float* __restrict__ bg, unsigned short* __restrict__ kv,
    float* __restrict__ qpart, unsigned short* __restrict__ g_ws) {
  __shared__ unsigned short xt[4][16 * 72];  // per-wave bf16 tile, pad 72
  __shared__ float lnw[64], lnb[64];
  __shared__ float qred[4][64];

  const int t = threadIdx.x;
  const int w = t >> 6, l = t & 63;
  const int lane_n = l & 15, quad = l >> 4;
  const int r = blockIdx.y, chunk = blockIdx.x;

  if (t < 64) { lnw[t] = lnw_g[t]; lnb[t] = lnb_g[t]; }

  // B-frags in registers: [Wk|Wv] (N=16) and Wg (N=64), K=64 -> 2 frags each.
  bf16x8 bkv[2];
  bf16x8 Bg[4][2];
  float bgv[4];
#pragma unroll
  for (int kk = 0; kk < 2; ++kk) {
#pragma unroll
    for (int j = 0; j < 8; ++j) {
      const int k = kk * 32 + quad * 8 + j;
      const float wv_ = (lane_n < 8) ? Wk[k * 8 + lane_n] : Wv[k * 8 + lane_n - 8];
      ((unsigned short*)&bkv[kk])[j] = f2bf(wv_);
    }
  }
#pragma unroll
  for (int n = 0; n < 4; ++n) {
    bgv[n] = bg[n * 16 + lane_n];
#pragma unroll
    for (int kk = 0; kk < 2; ++kk) {
#pragma unroll
      for (int j = 0; j < 8; ++j) {
        const int k = kk * 32 + quad * 8 + j;
        ((unsigned short*)&Bg[n][kk])[j] = f2bf(Wg[k * 64 + n * 16 + lane_n]);
      }
    }
  }
  __syncthreads();

  unsigned short* xw = xt[w];
  const int c4 = lane_n * 4;
  float4 qacc = make_float4(0.f, 0.f, 0.f, 0.f);

  for (int it = 0; it < 4; ++it) {
    const int s0 = chunk * 256 + it * 64 + w * 16;
#pragma unroll
    for (int p = 0; p < 4; ++p) {
      const int row = p * 4 + quad;
      const float4 x4 = *(const float4*)(m + ((size_t)(s0 + row) * R_ + r) * 64 + c4);
      const float4 xl = ln_quad(x4, lnw, lnb, c4);
      qacc.x += xl.x; qacc.y += xl.y; qacc.z += xl.z; qacc.w += xl.w;
      ushort4 pk;
      pk.x = f2bf(xl.x); pk.y = f2bf(xl.y); pk.z = f2bf(xl.z); pk.w = f2bf(xl.w);
      *(ushort4*)(xw + row * 72 + c4) = pk;
    }
    __builtin_amdgcn_wave_barrier();
    const bf16x8 a0 = *(const bf16x8*)(xw + lane_n * 72 + quad * 8);
    const bf16x8 a1 = *(const bf16x8*)(xw + lane_n * 72 + 32 + quad * 8);
    // K/V projection
    f32x4 acc = {0.f, 0.f, 0.f, 0.f};
    acc = mfma16(a0, bkv[0], acc);
    acc = mfma16(a1, bkv[1], acc);
    // gate GEMM
    f32x4 gacc[4];
#pragma unroll
    for (int n = 0; n < 4; ++n) {
      f32x4 z = {0.f, 0.f, 0.f, 0.f};
      z = mfma16(a0, Bg[n][0], z);
      gacc[n] = mfma16(a1, Bg[n][1], z);
    }
#pragma unroll
    for (int rg = 0; rg < 4; ++rg)
      kv[((size_t)r * S_ + s0 + quad * 4 + rg) * 16 + lane_n] = f2bf(acc[rg]);
    __builtin_amdgcn_wave_barrier();
    // sigmoid gate -> bf16 -> LDS tile row-major [s][hc]
#pragma unroll
    for (int n = 0; n < 4; ++n) {
#pragma unroll
      for (int reg = 0; reg < 4; ++reg) {
        const float gv = 1.f / (1.f + __expf(-(gacc[n][reg] + bgv[n])));
        xw[(quad * 4 + reg) * 72 + n * 16 + lane_n] = f2bf(gv);
      }
    }
    __builtin_amdgcn_wave_barrier();
    // vectorized g store: 2 passes, lane -> 16B of one s-row (128B/row contig)
#pragma unroll
    for (int pp = 0; pp < 2; ++pp) {
      const int row = pp * 8 + (l >> 3), hc8 = (l & 7) * 8;
      const bf16x8 gv = *(const bf16x8*)(xw + row * 72 + hc8);
      *(bf16x8*)(g_ws + ((size_t)(s0 + row) * R_ + r) * 64 + hc8) = gv;
    }
    __builtin_amdgcn_wave_barrier();
  }

  // reduce q partials across row slots (lane bits 4,5)
#pragma unroll
  for (int msk = 16; msk <= 32; msk <<= 1) {
    qacc.x += __shfl_xor(qacc.x, msk);
    qacc.y += __shfl_xor(qacc.y, msk);
    qacc.z += __shfl_xor(qacc.z, msk);
    qacc.w += __shfl_xor(qacc.w, msk);
  }
  if (l < 16) *(float4*)(&qred[w][c4]) = qacc;
  __syncthreads();
  if (t < 64)
    qpart[((size_t)chunk * R_ + r) * 64 + t] =
        qred[0][t] + qred[1][t] + qred[2][t] + qred[3][t];
}

// ---- Kernel 2: pooled q + chunked partial softmax ----
// grid (8, R), block 256. Block handles 256 s-rows; logits live in registers.
// apart[r][chunk][h]: {m, l, ov[8]}  (10 floats)
__global__ __launch_bounds__(256) void k_attn(
    const float* __restrict__ qpart, const float* __restrict__ Wq,
    const unsigned short* __restrict__ kv, float* __restrict__ apart) {
  __shared__ float qs[64];
  __shared__ float q[64];
  __shared__ float mred[8 * 32];
  __shared__ float mhs[8];
  __shared__ float lred[8 * 32];
  __shared__ float opart[32 * 64];

  const int t = threadIdx.x;
  const int chunk = blockIdx.x, r = blockIdx.y;

  if (t < 64) {
    float s = 0.f;
#pragma unroll
    for (int ch = 0; ch < 8; ++ch) s += qpart[((size_t)ch * R_ + r) * 64 + t];
    qs[t] = s * (1.f / 2048.f);   // /(S+1e-10) rounds to /2048 in fp32
  }
  __syncthreads();
  if (t < 64) {
    float acc = 0.f;
    for (int c = 0; c < 64; ++c) acc = fmaf(qs[c], Wq[c * 64 + t], acc);
    q[t] = acc * 0.35355339059327373f;   // Ch^-0.5
  }
  __syncthreads();

  const int h = t & 7, part = t >> 3;   // 32 parts x 8 s-rows each
  float qh[8];
#pragma unroll
  for (int j = 0; j < 8; ++j) qh[j] = q[h * 8 + j];

  const int sbase = chunk * 256 + part * 8;
  float d[8];
#pragma unroll
  for (int j = 0; j < 8; ++j) {
    const unsigned short* kp = kv + ((size_t)r * S_ + sbase + j) * 16;
    const uint4 kr = *(const uint4*)kp;
    float dd;
    dd = qh[0] * bflo(kr.x) + qh[1] * bfhi(kr.x);
    dd = fmaf(qh[2], bflo(kr.y), fmaf(qh[3], bfhi(kr.y), dd));
    dd = fmaf(qh[4], bflo(kr.z), fmaf(qh[5], bfhi(kr.z), dd));
    dd = fmaf(qh[6], bflo(kr.w), fmaf(qh[7], bfhi(kr.w), dd));
    d[j] = dd;
  }
  float mx = -1e30f;
#pragma unroll
  for (int j = 0; j < 8; ++j) mx = fmaxf(mx, d[j]);
  mred[h * 32 + part] = mx;
  __syncthreads();
  if (t < 8) {
    float mh_ = -1e30f;
    for (int p = 0; p < 32; ++p) mh_ = fmaxf(mh_, mred[t * 32 + p]);
    mhs[t] = mh_;
  }
  __syncthreads();
  const float mh = mhs[h];

  float l_acc = 0.f;
  float av[8];
#pragma unroll
  for (int j = 0; j < 8; ++j) av[j] = 0.f;
#pragma unroll
  for (int j = 0; j < 8; ++j) {
    const unsigned short* kp = kv + ((size_t)r * S_ + sbase + j) * 16;
    const uint4 vr = *(const uint4*)(kp + 8);
    const float e = __expf(d[j] - mh);
    l_acc += e;
    av[0] = fmaf(e, bflo(vr.x), av[0]); av[1] = fmaf(e, bfhi(vr.x), av[1]);
    av[2] = fmaf(e, bflo(vr.y), av[2]); av[3] = fmaf(e, bfhi(vr.y), av[3]);
    av[4] = fmaf(e, bflo(vr.z), av[4]); av[5] = fmaf(e, bfhi(vr.z), av[5]);
    av[6] = fmaf(e, bflo(vr.w), av[6]); av[7] = fmaf(e, bfhi(vr.w), av[7]);
  }
  lred[h * 32 + part] = l_acc;
#pragma unroll
  for (int j = 0; j < 8; ++j) opart[part * 64 + h * 8 + j] = av[j];
  __syncthreads();

  if (t < 64) {
    const int hh = t >> 3, jj = t & 7;
    float L = 0.f;
    for (int p = 0; p < 32; ++p) L += lred[hh * 32 + p];
    float O = 0.f;
    for (int p = 0; p < 32; ++p) O += opart[p * 64 + t];
    float* ap = apart + (((size_t)r * 8 + chunk) * 8 + hh) * 10;
    if (jj == 0) { ap[0] = mhs[hh]; ap[1] = L; }
    ap[2 + jj] = O;
  }
}

// ---- Kernel 3: attn combine + output GEMM (o folded into Wo) ----
// grid (8, R), block 256 (4 waves). Reads bf16 g, writes out via LDS transpose.
__global__ __launch_bounds__(256) void k_out(
    const unsigned short* __restrict__ g_ws, const float* __restrict__ apart,
    const float* __restrict__ Wo, const float* __restrict__ bo,
    float* __restrict__ out) {
  __shared__ float osm[64];
  union TileU {
    unsigned short xt[16 * 72];  // bf16 g tile (pad 72)
    float ot[16 * 68];           // f32 out tile (pad 68)
  };
  __shared__ __align__(16) TileU tiles[4];

  const int t = threadIdx.x;
  const int w = t >> 6, l = t & 63;
  const int lane_n = l & 15, quad = l >> 4;
  const int r = blockIdx.y, chunk = blockIdx.x;

  // exact combine of 8 chunk-partials: o[h*8+j]
  if (t < 64) {
    const int h = t >> 3, j = t & 7;
    float M = -1e30f;
#pragma unroll
    for (int c = 0; c < 8; ++c)
      M = fmaxf(M, apart[(((size_t)r * 8 + c) * 8 + h) * 10]);
    float L = 0.f, O = 0.f;
#pragma unroll
    for (int c = 0; c < 8; ++c) {
      const float* ap = apart + (((size_t)r * 8 + c) * 8 + h) * 10;
      const float wgt = __expf(ap[0] - M);
      L = fmaf(ap[1], wgt, L);
      O = fmaf(ap[2 + j], wgt, O);
    }
    osm[t] = O / L;
  }
  __syncthreads();

  // weight frags: o .* Wo, 4 N-tiles x 2 K-steps
  bf16x8 Bo[4][2];
  float bov[4];
#pragma unroll
  for (int n = 0; n < 4; ++n) {
    bov[n] = bo[n * 16 + lane_n];
#pragma unroll
    for (int kk = 0; kk < 2; ++kk) {
#pragma unroll
      for (int j = 0; j < 8; ++j) {
        const int k = kk * 32 + quad * 8 + j;
        ((unsigned short*)&Bo[n][kk])[j] = f2bf(osm[k] * Wo[k * 64 + n * 16 + lane_n]);
      }
    }
  }

  unsigned short* xw = tiles[w].xt;
  float* ow = tiles[w].ot;

  for (int it = 0; it < 4; ++it) {
    const int s0 = chunk * 256 + it * 64 + w * 16;
    // stage g: 2 passes, lane loads 16B (128B contig per s-row)
#pragma unroll
    for (int pp = 0; pp < 2; ++pp) {
      const int row = pp * 8 + (l >> 3), hc8 = (l & 7) * 8;
      const bf16x8 gv = *(const bf16x8*)(g_ws + ((size_t)(s0 + row) * R_ + r) * 64 + hc8);
      *(bf16x8*)(xw + row * 72 + hc8) = gv;
    }
    __builtin_amdgcn_wave_barrier();
    const bf16x8 g0 = *(const bf16x8*)(xw + lane_n * 72 + quad * 8);
    const bf16x8 g1 = *(const bf16x8*)(xw + lane_n * 72 + 32 + quad * 8);
    f32x4 oacc[4];
#pragma unroll
    for (int n = 0; n < 4; ++n) {
      f32x4 z = {0.f, 0.f, 0.f, 0.f};
      z = mfma16(g0, Bo[n][0], z);
      oacc[n] = mfma16(g1, Bo[n][1], z);
    }
    __builtin_amdgcn_wave_barrier();
    // transpose through LDS for vectorized stores
#pragma unroll
    for (int n = 0; n < 4; ++n) {
#pragma unroll
      for (int reg = 0; reg < 4; ++reg)
        ow[(quad * 4 + reg) * 68 + n * 16 + lane_n] = oacc[n][reg] + bov[n];
    }
    __builtin_amdgcn_wave_barrier();
#pragma unroll
    for (int pp = 0; pp < 4; ++pp) {
      const int row = pp * 4 + (l >> 4), cc = (l & 15) * 4;
      const float4 ov = *(const float4*)(ow + row * 68 + cc);
      *(float4*)(out + ((size_t)(s0 + row) * R_ + r) * 64 + cc) = ov;
    }
    __builtin_amdgcn_wave_barrier();
  }
}

extern "C" void kernel_launch(void* const* d_in, const int* in_sizes, int n_in,
                              void* d_out, int out_size, void* d_ws, size_t ws_size,
                              hipStream_t stream) {
  (void)in_sizes; (void)n_in; (void)out_size; (void)ws_size;
  const float* m   = (const float*)d_in[0];
  const float* lnw = (const float*)d_in[1];
  const float* lnb = (const float*)d_in[2];
  const float* Wq  = (const float*)d_in[3];
  const float* Wk  = (const float*)d_in[4];
  const float* Wv  = (const float*)d_in[5];
  const float* Wg  = (const float*)d_in[6];
  const float* bg  = (const float*)d_in[7];
  const float* Wo  = (const float*)d_in[8];
  const float* bo  = (const float*)d_in[9];
  float* out = (float*)d_out;

  // ws layout: kv bf16 [R*S*16] | qpart f32 [8*R*64] | apart f32 [R*8*8*10]
  //          | g bf16 [S*R*64]                                   (~128 MB)
  unsigned short* kv = (unsigned short*)d_ws;
  float* qpart = (float*)((char*)d_ws + (size_t)R_ * S_ * 16 * 2);
  float* apart = qpart + (size_t)8 * R_ * 64;
  unsigned short* g_ws = (unsigned short*)(apart + (size_t)R_ * 8 * 8 * 10);

  k_lnkv<<<dim3(8, R_), 256, 0, stream>>>(m, lnw, lnb, Wk, Wv, Wg, bg, kv, qpart, g_ws);
  k_attn<<<dim3(8, R_), 256, 0, stream>>>(qpart, Wq, kv, apart);
  k_out<<<dim3(8, R_), 256, 0, stream>>>(g_ws, apart, Wo, bo, out);
}